// Round 4
// baseline (2426.537 us; speedup 1.0000x reference)
//
#include <hip/hip_runtime.h>

typedef __bf16 bf16_t;
typedef bf16_t bf16x8 __attribute__((ext_vector_type(8)));
typedef float f32x16 __attribute__((ext_vector_type(16)));

#define NSAMP 1000000
#define NFEAT 64
#define NCLUS 128
#define NITER 5
#define NPART 64
#define ATHREADS 256
#define ABLOCKS 1563          // 6252 waves over 31250 tiles -> ~5 tiles/wave
#define NWTILE (NSAMP / 32)   // 31250 wave-tiles of 32 samples
#define LPAD 65               // lsum row pad: bank = (lab + feat) & 31

// ---------------- prep: Cbf2 = -2*C0 (bf16), c2 (f32), zero accumulators ----------------
__global__ void prep_centroids(const float* __restrict__ C0, bf16_t* __restrict__ Cbf2,
                               float* __restrict__ c2, float* __restrict__ psum,
                               float* __restrict__ pcount, float* __restrict__ inert,
                               float* __restrict__ sx2) {
    int k = blockIdx.x;    // 0..127
    int f = threadIdx.x;   // 0..63
    float v = C0[k * NFEAT + f];
    Cbf2[k * NFEAT + f] = (bf16_t)(-2.f * v);
    float s = v * v;
    #pragma unroll
    for (int off = 32; off; off >>= 1) s += __shfl_down(s, off, 64);
    if (f == 0) c2[k] = s;

    int tid = k * 64 + f;  // 0..8191
    for (int idx = tid; idx < NPART * NCLUS * NFEAT; idx += 8192) psum[idx] = 0.f;
    for (int idx = tid; idx < NPART * NCLUS; idx += 8192) pcount[idx] = 0.f;
    if (tid < 8) inert[tid] = 0.f;
    if (tid == 8) sx2[0] = 0.f;
}

// -------- convert X -> bf16 (stores only when WRITE), accumulate Sx2 from f32 X --------
template<bool WRITE>
__global__ void convert_x_kernel(const float* __restrict__ X, bf16_t* __restrict__ Xbf,
                                 float* __restrict__ sx2) {
    const size_t total = (size_t)NSAMP * NFEAT / 8;   // 8M groups of 8 floats
    const size_t stride = (size_t)gridDim.x * blockDim.x;
    float s = 0.f;
    for (size_t t = (size_t)blockIdx.x * blockDim.x + threadIdx.x; t < total; t += stride) {
        float4 v0 = ((const float4*)X)[t * 2];
        float4 v1 = ((const float4*)X)[t * 2 + 1];
        s += v0.x*v0.x + v0.y*v0.y + v0.z*v0.z + v0.w*v0.w
           + v1.x*v1.x + v1.y*v1.y + v1.z*v1.z + v1.w*v1.w;
        if constexpr (WRITE) {
            union { unsigned short us[8]; uint4 v; } u;
            u.us[0] = __builtin_bit_cast(unsigned short, (bf16_t)v0.x);
            u.us[1] = __builtin_bit_cast(unsigned short, (bf16_t)v0.y);
            u.us[2] = __builtin_bit_cast(unsigned short, (bf16_t)v0.z);
            u.us[3] = __builtin_bit_cast(unsigned short, (bf16_t)v0.w);
            u.us[4] = __builtin_bit_cast(unsigned short, (bf16_t)v1.x);
            u.us[5] = __builtin_bit_cast(unsigned short, (bf16_t)v1.y);
            u.us[6] = __builtin_bit_cast(unsigned short, (bf16_t)v1.z);
            u.us[7] = __builtin_bit_cast(unsigned short, (bf16_t)v1.w);
            ((uint4*)Xbf)[t] = u.v;
        }
    }
    #pragma unroll
    for (int off = 32; off; off >>= 1) s += __shfl_down(s, off, 64);
    if ((threadIdx.x & 63) == 0) atomicAdd(sx2, s);
}

// ------- assign: swapped MFMA (clusters=M, samples=N cols), lane-local argmin -------
template<bool XBF>
__global__ __launch_bounds__(ATHREADS, 3) void assign_kernel(
    const float* __restrict__ X, const bf16_t* __restrict__ Xbf,
    const bf16_t* __restrict__ Cbf2, const float* __restrict__ c2g,
    float* __restrict__ labelsF, float* __restrict__ psum,
    float* __restrict__ pcount, float* __restrict__ inertOut, int last) {
    __shared__ float lsum[NCLUS * LPAD];
    __shared__ float lcount[NCLUS];
    __shared__ float linert;

    const int tid = threadIdx.x;
    for (int i = tid; i < NCLUS * LPAD; i += ATHREADS) lsum[i] = 0.f;
    if (tid < NCLUS) lcount[tid] = 0.f;
    if (tid == 0) linert = 0.f;
    __syncthreads();

    const int lane = tid & 63;
    const int wave = tid >> 6;
    const int cm = lane & 31;    // A: cluster row within tile; B/D: sample column
    const int hi = lane >> 5;    // k-half selector
    const int hi8 = hi * 8;
    const unsigned base4 = 4u * (unsigned)hi;   // D-row component from lane

    // Loop-invariant A fragments: -2*C; tile t covers clusters [t*32, t*32+32)
    bf16x8 areg[4][4];
    #pragma unroll
    for (int t = 0; t < 4; ++t)
        #pragma unroll
        for (int kk = 0; kk < 4; ++kk)
            areg[t][kk] = *reinterpret_cast<const bf16x8*>(
                Cbf2 + (t * 32 + cm) * NFEAT + kk * 16 + hi8);

    // c2 fold: A'[cluster][k0]=c2_hi, A'[cluster][k1]=c2_lo; B'[k0]=B'[k1]=1 (all cols)
    bf16x8 bones; bf16x8 aq[4];
    #pragma unroll
    for (int e = 0; e < 8; ++e) bones[e] = (bf16_t)0.f;
    if (hi == 0) { bones[0] = (bf16_t)1.0f; bones[1] = (bf16_t)1.0f; }
    #pragma unroll
    for (int t = 0; t < 4; ++t) {
        bf16x8 a;
        #pragma unroll
        for (int e = 0; e < 8; ++e) a[e] = (bf16_t)0.f;
        if (hi == 0) {
            float cv = c2g[t * 32 + cm];
            bf16_t ch = (bf16_t)cv;
            a[0] = ch; a[1] = (bf16_t)(cv - (float)ch);
        }
        aq[t] = a;
    }

    float my_in = 0.f;
    for (int wt = blockIdx.x * 4 + wave; wt < NWTILE; wt += ABLOCKS * 4) {
        const int i0 = wt * 32;
        bf16x8 breg[4];   // sample cm's features: kk*16 + hi8 + e
        if constexpr (XBF) {
            const bf16_t* bp = Xbf + (size_t)(i0 + cm) * NFEAT + hi8;
            #pragma unroll
            for (int kk = 0; kk < 4; ++kk)
                breg[kk] = *reinterpret_cast<const bf16x8*>(bp + kk * 16);
        } else {
            const float* bp = X + (size_t)(i0 + cm) * NFEAT + hi8;
            #pragma unroll
            for (int kk = 0; kk < 4; ++kk) {
                float4 v0 = *(const float4*)(bp + kk * 16);
                float4 v1 = *(const float4*)(bp + kk * 16 + 4);
                bf16x8 b;
                b[0] = (bf16_t)v0.x; b[1] = (bf16_t)v0.y; b[2] = (bf16_t)v0.z; b[3] = (bf16_t)v0.w;
                b[4] = (bf16_t)v1.x; b[5] = (bf16_t)v1.y; b[6] = (bf16_t)v1.z; b[7] = (bf16_t)v1.w;
                breg[kk] = b;
            }
        }

        // 4 sequential M-tiles, acc reused; running u32-key min (dist | cluster)
        unsigned best = 0xFFFFFFFFu;
        #pragma unroll
        for (int t = 0; t < 4; ++t) {
            f32x16 acc;
            #pragma unroll
            for (int r = 0; r < 16; ++r) acc[r] = 0.f;
            acc = __builtin_amdgcn_mfma_f32_32x32x16_bf16(areg[t][0], breg[0], acc, 0, 0, 0);
            acc = __builtin_amdgcn_mfma_f32_32x32x16_bf16(areg[t][1], breg[1], acc, 0, 0, 0);
            acc = __builtin_amdgcn_mfma_f32_32x32x16_bf16(areg[t][2], breg[2], acc, 0, 0, 0);
            acc = __builtin_amdgcn_mfma_f32_32x32x16_bf16(areg[t][3], breg[3], acc, 0, 0, 0);
            acc = __builtin_amdgcn_mfma_f32_32x32x16_bf16(aq[t], bones, acc, 0, 0, 0);
            // acc[r] = c2[k] - 2*dot(x, c_k), k = t*32 + (r&3) + 8*(r>>2) + 4*hi
            #pragma unroll
            for (int r = 0; r < 16; ++r) {
                unsigned key = (__builtin_bit_cast(unsigned, acc[r] + 256.0f) & 0xFFFFFF80u)
                             | (unsigned)(t * 32 + (r & 3) + 8 * (r >> 2)) | base4;
                best = key < best ? key : best;
            }
        }
        {   // combine the two lane halves (complementary cluster subsets)
            unsigned o = (unsigned)__shfl_xor((int)best, 32, 64);
            best = o < best ? o : best;
        }
        const int lab = (int)(best & 127u);

        // centroid sums straight from B fragments (each lane owns 32 distinct feats)
        #pragma unroll
        for (int kk = 0; kk < 4; ++kk)
            #pragma unroll
            for (int e = 0; e < 8; ++e)
                atomicAdd(&lsum[lab * LPAD + kk * 16 + hi8 + e], (float)breg[kk][e]);

        if (hi == 0) {
            atomicAdd(&lcount[lab], 1.f);
            my_in += __builtin_bit_cast(float, best & 0xFFFFFF80u) - 256.0f;  // min(c2-2dot)
            if (last) labelsF[i0 + cm] = (float)lab;
        }
    }

    #pragma unroll
    for (int off = 32; off; off >>= 1) my_in += __shfl_down(my_in, off, 64);
    if (lane == 0) atomicAdd(&linert, my_in);
    __syncthreads();

    const int part = blockIdx.x & (NPART - 1);
    for (int idx = tid; idx < NCLUS * NFEAT; idx += ATHREADS) {
        float v = lsum[(idx >> 6) * LPAD + (idx & 63)];
        if (v != 0.f) atomicAdd(&psum[part * (NCLUS * NFEAT) + idx], v);
    }
    for (int idx = tid; idx < NCLUS; idx += ATHREADS) {
        float v = lcount[idx];
        if (v != 0.f) atomicAdd(&pcount[part * NCLUS + idx], v);
    }
    if (tid == 0) atomicAdd(inertOut, linert);
}

// ---------------- update: reduce partials, means/reseed, next Cbf2/c2 ----------------
__global__ void update_kernel(const float* __restrict__ X,
                              const int* __restrict__ reseed,
                              float* __restrict__ psum, float* __restrict__ pcount,
                              bf16_t* __restrict__ Cbf2, float* __restrict__ c2,
                              float* __restrict__ outC,
                              const float* __restrict__ inertIn,
                              const float* __restrict__ sx2,
                              float* __restrict__ outInert, int last) {
    int k = blockIdx.x;    // cluster
    int f = threadIdx.x;   // feature (one wave)

    float s = 0.f;
    #pragma unroll 8
    for (int p = 0; p < NPART; ++p) {
        int idx = p * (NCLUS * NFEAT) + k * NFEAT + f;
        s += psum[idx];
        psum[idx] = 0.f;
    }
    float cnt = pcount[f * NCLUS + k];   // thread f owns partial copy p=f
    pcount[f * NCLUS + k] = 0.f;
    #pragma unroll
    for (int off = 32; off; off >>= 1) cnt += __shfl_xor(cnt, off, 64);

    float val;
    if (cnt > 0.f) val = s / cnt;
    else           val = X[(size_t)reseed[k] * NFEAT + f];   // exact f32 reseed

    outC[k * NFEAT + f] = val;
    Cbf2[k * NFEAT + f] = (bf16_t)(-2.f * val);
    float q = val * val;
    #pragma unroll
    for (int off = 32; off; off >>= 1) q += __shfl_xor(q, off, 64);
    if (f == 0) c2[k] = q;

    if (last && k == 0 && f == 0) *outInert = inertIn[0] + sx2[0];
}

extern "C" void kernel_launch(void* const* d_in, const int* in_sizes, int n_in,
                              void* d_out, int out_size, void* d_ws, size_t ws_size,
                              hipStream_t stream) {
    const float* X      = (const float*)d_in[0];
    const float* C0     = (const float*)d_in[1];
    const int*   reseed = (const int*)d_in[2];

    float* out      = (float*)d_out;
    float* outC     = out;                          // [128*64]
    float* labelsF  = out + NCLUS * NFEAT;          // [1M]
    float* outInert = out + NCLUS * NFEAT + NSAMP;  // [1]

    float* ws     = (float*)d_ws;
    float* psum   = ws;                                   // 64*8192
    float* pcount = psum + NPART * NCLUS * NFEAT;         // 64*128
    float* c2     = pcount + NPART * NCLUS;               // 128
    float* inert  = c2 + NCLUS;                           // 8
    float* sx2    = inert + 8;                            // 1 (+pad)
    bf16_t* Cbf2  = (bf16_t*)(sx2 + 8);                   // 8192 bf16 (16 KB)
    bf16_t* Xbf   = Cbf2 + NCLUS * NFEAT;                 // 64M bf16 (128 MB), optional

    const size_t base_bytes = (size_t)(NPART * NCLUS * NFEAT + NPART * NCLUS + NCLUS + 16) * 4
                            + (size_t)NCLUS * NFEAT * 2;
    const bool xbf = ws_size >= base_bytes + (size_t)NSAMP * NFEAT * 2;

    prep_centroids<<<NCLUS, 64, 0, stream>>>(C0, Cbf2, c2, psum, pcount, inert, sx2);
    if (xbf) convert_x_kernel<true><<<2048, 256, 0, stream>>>(X, Xbf, sx2);
    else     convert_x_kernel<false><<<2048, 256, 0, stream>>>(X, Xbf, sx2);

    for (int i = 0; i < NITER; ++i) {
        int last = (i == NITER - 1);
        if (xbf)
            assign_kernel<true><<<ABLOCKS, ATHREADS, 0, stream>>>(
                X, Xbf, Cbf2, c2, labelsF, psum, pcount, inert + i, last);
        else
            assign_kernel<false><<<ABLOCKS, ATHREADS, 0, stream>>>(
                X, Xbf, Cbf2, c2, labelsF, psum, pcount, inert + i, last);
        update_kernel<<<NCLUS, 64, 0, stream>>>(X, reseed + i * NCLUS, psum, pcount,
                                                Cbf2, c2, outC, inert + (NITER - 1),
                                                sx2, outInert, last);
    }
}